// Round 7
// baseline (468.231 us; speedup 1.0000x reference)
//
#include <hip/hip_runtime.h>
#include <hip/hip_bf16.h>

#define NN 1048576
#define NG 16384
#define DD 128
#define GRIDB 1024
#define WSTRIDE (GRIDB * 4)   // 4096 waves, interleaved: wave p <- graphs p, p+4096, ...

typedef __bf16 bf16x8 __attribute__((ext_vector_type(8)));
typedef float f32x4 __attribute__((ext_vector_type(4)));

__device__ __forceinline__ unsigned short f2bf(float f) {
    unsigned int u = __float_as_uint(f);
    u += 0x7FFFu + ((u >> 16) & 1u);
    return (unsigned short)(u >> 16);
}

__global__ void prep_kernel(const int* __restrict__ gid, const float* __restrict__ W,
                            int* __restrict__ starts, unsigned short* __restrict__ Wl) {
    int t = blockIdx.x * 256 + threadIdx.x;
    if (t <= NG) {
        int lo = 0, hi = NN;
        while (lo < hi) { int mid = (lo + hi) >> 1; if (gid[mid] < t) lo = mid + 1; else hi = mid; }
        starts[t] = lo;
    }
    if (t < DD * DD) {
        // fragment-ordered B: Wl[((n*4+kk)*64 + l)*8 + e] = bf16(W[k][col]),
        // k = kk*32 + (l>>4)*8 + e, col = n*16 + (l&15)
        int e = t & 7, l = (t >> 3) & 63, kk = (t >> 9) & 3, n = t >> 11;
        int k = kk * 32 + (l >> 4) * 8 + e;
        int col = n * 16 + (l & 15);
        Wl[t] = f2bf(W[k * DD + col]);
    }
}

// Wave-per-graph, interleaved mapping (proven fastest DRAM pattern: the whole
// chip walks x as one coherent moving window). No LDS arrays, no barriers:
// x A-fragments are loaded just-in-time into registers and consumed
// immediately (no long-lived prefetch regs -> no scratch spills). Occupancy is
// VGPR-limited (~12 waves/CU), giving TLP to hide each tile's exposed latency.
__global__ __launch_bounds__(256, 3) void fused_kernel(
    const float* __restrict__ x, const int* __restrict__ starts,
    const unsigned short* __restrict__ Wl,
    const float* __restrict__ b_enc, const float* __restrict__ w_q1,
    const float* __restrict__ b_q1, const float* __restrict__ w_q2,
    const float* __restrict__ b_q2, float* __restrict__ out) {

    const int t = threadIdx.x, w = t >> 6, l = t & 63;
    const int lr = l & 15, lk = l >> 4;

    // W fragments -> registers (loop-invariant, L1-served broadcast)
    bf16x8 wfr[8][4];
#pragma unroll
    for (int n = 0; n < 8; ++n)
#pragma unroll
        for (int kk = 0; kk < 4; ++kk)
            wfr[n][kk] = *(const bf16x8*)&Wl[((n * 4 + kk) * 64 + l) * 8];

    float br[8], w1r[8], w2r[8];
#pragma unroll
    for (int n = 0; n < 8; ++n) {
        br[n]  = b_enc[n * 16 + lr];
        w1r[n] = w_q1[n * 16 + lr];
        w2r[n] = w_q2[n * 16 + lr];
    }
    const float bq1 = b_q1[0], bq2 = b_q2[0];

    const int g0 = blockIdx.x * 4 + w;

    for (int cg = g0; cg < NG; cg += WSTRIDE) {
        const int cs0 = starts[cg], cs1 = starts[cg + 1];
        const int cnt = cs1 - cs0;

        float m1 = -1e30f, m2 = -1e30f, z1 = 0.f, z2 = 0.f;
        float ka[8], q1a[8], q2a[8];
#pragma unroll
        for (int n = 0; n < 8; ++n) { ka[n] = 0.f; q1a[n] = 0.f; q2a[n] = 0.f; }

        for (int cc0 = cs0; cc0 < cs1; cc0 += 16) {
            // ---- JIT load + convert: lane l needs row (cc0+lr), k-slice lk*8 (+kk*32) ----
            const int grow = min(cc0 + lr, cs1 - 1);     // clamp tail (masked later)
            const float* xp = x + (size_t)grow * DD + lk * 8;
            bf16x8 afr[4];
#pragma unroll
            for (int kk = 0; kk < 4; ++kk) {
                const float4 f0 = *(const float4*)(xp + kk * 32);
                const float4 f1 = *(const float4*)(xp + kk * 32 + 4);
                bf16x8 a;
                a[0] = (__bf16)f0.x; a[1] = (__bf16)f0.y; a[2] = (__bf16)f0.z; a[3] = (__bf16)f0.w;
                a[4] = (__bf16)f1.x; a[5] = (__bf16)f1.y; a[6] = (__bf16)f1.z; a[7] = (__bf16)f1.w;
                afr[kk] = a;
            }

            // ---- MFMA: h[16 x 128] (A from regs, B from regs) ----
            f32x4 acc[8];
#pragma unroll
            for (int n = 0; n < 8; ++n) { acc[n][0] = 0.f; acc[n][1] = 0.f; acc[n][2] = 0.f; acc[n][3] = 0.f; }
#pragma unroll
            for (int n = 0; n < 8; ++n)
#pragma unroll
                for (int kk = 0; kk < 4; ++kk)
                    acc[n] = __builtin_amdgcn_mfma_f32_16x16x32_bf16(afr[kk], wfr[n][kk], acc[n], 0, 0, 0);

            // ---- bias+relu, score partials (C: col=n*16+lr, row=lk*4+j) ----
            float p1[4] = {0.f, 0.f, 0.f, 0.f}, p2[4] = {0.f, 0.f, 0.f, 0.f};
#pragma unroll
            for (int n = 0; n < 8; ++n) {
#pragma unroll
                for (int j = 0; j < 4; ++j) {
                    float hv = fmaxf(acc[n][j] + br[n], 0.f);
                    acc[n][j] = hv;
                    p1[j] += hv * w1r[n];
                    p2[j] += hv * w2r[n];
                }
            }
#pragma unroll
            for (int j = 0; j < 4; ++j)
#pragma unroll
                for (int d = 1; d < 16; d <<= 1) {
                    p1[j] += __shfl_xor(p1[j], d);
                    p2[j] += __shfl_xor(p2[j], d);
                }

            // ---- per-wave online softmax over 16 rows ----
            float v1[4], v2[4];
            float r1 = -1e30f, r2 = -1e30f;
#pragma unroll
            for (int j = 0; j < 4; ++j) {
                const bool vv = (cc0 + lk * 4 + j) < cs1;
                v1[j] = vv ? p1[j] + bq1 : -1e30f;
                v2[j] = vv ? p2[j] + bq2 : -1e30f;
                r1 = fmaxf(r1, v1[j]); r2 = fmaxf(r2, v2[j]);
            }
            r1 = fmaxf(r1, __shfl_xor(r1, 16)); r1 = fmaxf(r1, __shfl_xor(r1, 32));
            r2 = fmaxf(r2, __shfl_xor(r2, 16)); r2 = fmaxf(r2, __shfl_xor(r2, 32));

            const float nm1 = fmaxf(m1, r1), nm2 = fmaxf(m2, r2);
            const float sc1 = __expf(m1 - nm1), sc2 = __expf(m2 - nm2);
            float e1j[4], e2j[4];
            float cz1 = 0.f, cz2 = 0.f;
#pragma unroll
            for (int j = 0; j < 4; ++j) {
                e1j[j] = __expf(v1[j] - nm1);
                e2j[j] = __expf(v2[j] - nm2);
                cz1 += e1j[j]; cz2 += e2j[j];
            }
            cz1 += __shfl_xor(cz1, 16); cz1 += __shfl_xor(cz1, 32);
            cz2 += __shfl_xor(cz2, 16); cz2 += __shfl_xor(cz2, 32);
            z1 = z1 * sc1 + cz1; z2 = z2 * sc2 + cz2;
            m1 = nm1; m2 = nm2;

#pragma unroll
            for (int n = 0; n < 8; ++n) {
                float kaa = 0.f, q1aa = 0.f, q2aa = 0.f;
#pragma unroll
                for (int j = 0; j < 4; ++j) {
                    const float hv = acc[n][j];
                    const bool vv = (cc0 + lk * 4 + j) < cs1;
                    kaa  += vv ? hv : 0.f;
                    q1aa += e1j[j] * hv;
                    q2aa += e2j[j] * hv;
                }
                ka[n] += kaa;
                q1a[n] = q1a[n] * sc1 + q1aa;
                q2a[n] = q2a[n] * sc2 + q2aa;
            }
        }

        // ---- writeout: reduce over lk (bits 4,5), 2 cols per lane ----
#pragma unroll
        for (int n = 0; n < 8; ++n)
#pragma unroll
            for (int d = 16; d < 64; d <<= 1) {
                ka[n]  += __shfl_xor(ka[n],  d);
                q1a[n] += __shfl_xor(q1a[n], d);
                q2a[n] += __shfl_xor(q2a[n], d);
            }
        const float inv_cnt = 1.f / fmaxf((float)cnt, 1.f);
        const float iz1 = 1.f / fmaxf(z1, 1e-12f);
        const float iz2 = 1.f / fmaxf(z2, 1e-12f);
#pragma unroll
        for (int n2 = 0; n2 < 2; ++n2) {
            const int n = lk * 2 + n2;
            const int col = n * 16 + lr;
            out[(size_t)cg * DD + col]            = ka[n]  * inv_cnt;
            out[(size_t)(NG + cg) * DD + col]     = q1a[n] * iz1;
            out[(size_t)(2 * NG + cg) * DD + col] = q2a[n] * iz2;
        }
    }
}

extern "C" void kernel_launch(void* const* d_in, const int* in_sizes, int n_in,
                              void* d_out, int out_size, void* d_ws, size_t ws_size,
                              hipStream_t stream) {
    const float* x     = (const float*)d_in[0];
    const int*   gid   = (const int*)d_in[1];
    const float* W     = (const float*)d_in[2];
    const float* b_enc = (const float*)d_in[3];
    const float* w_q1  = (const float*)d_in[4];
    const float* b_q1  = (const float*)d_in[5];
    const float* w_q2  = (const float*)d_in[6];
    const float* b_q2  = (const float*)d_in[7];
    float* out = (float*)d_out;

    int* starts        = (int*)d_ws;                                // (NG+1) ints
    unsigned short* Wl = (unsigned short*)((char*)d_ws + 131072);   // 128*128 bf16, fragment-ordered

    prep_kernel<<<65, 256, 0, stream>>>(gid, W, starts, Wl);
    fused_kernel<<<GRIDB, 256, 0, stream>>>(x, starts, Wl, b_enc, w_q1, b_q1, w_q2, b_q2, out);
}

// Round 8
// 203.436 us; speedup vs baseline: 2.3016x; 2.3016x over previous
//
#include <hip/hip_runtime.h>
#include <hip/hip_bf16.h>

#define NN 1048576
#define NG 16384
#define DD 128
#define GRIDB 512
#define WPB 2                  // waves per block (128-thread blocks)
#define WSTRIDE (GRIDB * WPB)  // 1024 waves; window = 1024 graphs * ~32KB = 32 MB
#define RING 4                 // DMA ring depth per wave (4 x 8KB = 32 KB in flight)

typedef __bf16 bf16x8 __attribute__((ext_vector_type(8)));
typedef float f32x4 __attribute__((ext_vector_type(4)));

__device__ __forceinline__ unsigned short f2bf(float f) {
    unsigned int u = __float_as_uint(f);
    u += 0x7FFFu + ((u >> 16) & 1u);
    return (unsigned short)(u >> 16);
}

__global__ void prep_kernel(const int* __restrict__ gid, const float* __restrict__ W,
                            int* __restrict__ starts, unsigned short* __restrict__ Wl) {
    int t = blockIdx.x * 256 + threadIdx.x;
    if (t <= NG) {
        int lo = 0, hi = NN;
        while (lo < hi) { int mid = (lo + hi) >> 1; if (gid[mid] < t) lo = mid + 1; else hi = mid; }
        starts[t] = lo;
    }
    if (t < DD * DD) {
        // fragment-ordered B: Wl[((n*4+kk)*64 + l)*8 + e] = bf16(W[k][col]),
        // k = kk*32 + (l>>4)*8 + e, col = n*16 + (l&15)
        int e = t & 7, l = (t >> 3) & 63, kk = (t >> 9) & 3, n = t >> 11;
        int k = kk * 32 + (l >> 4) * 8 + e;
        int col = n * 16 + (l & 15);
        Wl[t] = f2bf(W[k * DD + col]);
    }
}

// R5 chassis (global_load_lds DMA, W in VGPRs, wave-per-graph interleaved, no
// barriers) with: 1024 waves (32 MB chip-wide moving window for DRAM density)
// and a depth-4 per-wave ring (32 KB in flight/wave) with counted vmcnt.
__global__ __launch_bounds__(128, 1) void fused_kernel(
    const float* __restrict__ x, const int* __restrict__ starts,
    const unsigned short* __restrict__ Wl,
    const float* __restrict__ b_enc, const float* __restrict__ w_q1,
    const float* __restrict__ b_q1, const float* __restrict__ w_q2,
    const float* __restrict__ b_q2, float* __restrict__ out) {

    __shared__ float xbuf[WPB][RING][16 * 128];   // 64 KB per block

    const int t = threadIdx.x, w = t >> 6, l = t & 63;
    const int lr = l & 15, lk = l >> 4;

    // W fragments -> registers (loop-invariant)
    bf16x8 wfr[8][4];
#pragma unroll
    for (int n = 0; n < 8; ++n)
#pragma unroll
        for (int kk = 0; kk < 4; ++kk)
            wfr[n][kk] = *(const bf16x8*)&Wl[((n * 4 + kk) * 64 + l) * 8];

    float br[8], w1r[8], w2r[8];
#pragma unroll
    for (int n = 0; n < 8; ++n) {
        br[n]  = b_enc[n * 16 + lr];
        w1r[n] = w_q1[n * 16 + lr];
        w2r[n] = w_q2[n * 16 + lr];
    }
    const float bq1 = b_q1[0], bq2 = b_q2[0];

    const int p = blockIdx.x * WPB + w;      // wave id 0..1023

    // ---- issue cursor (wave-uniform), interleaved graphs, skips empties ----
    int ig = p;
    int ic0 = starts[ig], is1 = starts[ig + 1];
    while (ic0 >= is1) {
        ig += WSTRIDE;
        if (ig >= NG) break;
        ic0 = starts[ig]; is1 = starts[ig + 1];
    }

    auto issue_tile = [&](int bufIdx) {
        const int hi = is1 - 1;
#pragma unroll
        for (int inst = 0; inst < 8; ++inst) {
            const int rit = inst * 2 + (l >> 5);            // row in tile 0..15
            const int grow = min(ic0 + rit, hi);            // clamped global row
            const int su = (l & 31) ^ (rit & 7);            // swizzled 16B unit
            const float* src = x + (size_t)grow * DD + su * 4;
            float* dst = &xbuf[w][bufIdx][inst * 256];      // wave-uniform base
            __builtin_amdgcn_global_load_lds(
                (const __attribute__((address_space(1))) void*)src,
                (__attribute__((address_space(3))) void*)dst, 16, 0, 0);
        }
    };
    auto adv_issue = [&]() {
        ic0 += 16;
        while (ic0 >= is1) {
            ig += WSTRIDE;
            if (ig >= NG) break;
            ic0 = starts[ig]; is1 = starts[ig + 1];
        }
    };

    int inflight = 0;
#pragma unroll
    for (int r = 0; r < RING; ++r)
        if (ig < NG) { issue_tile(r); adv_issue(); inflight++; }
    int buf = 0;

    for (int cg = p; cg < NG; cg += WSTRIDE) {
        const int cs0 = starts[cg], cs1 = starts[cg + 1];
        const int cnt = cs1 - cs0;

        float m1 = -1e30f, m2 = -1e30f, z1 = 0.f, z2 = 0.f;
        float ka[8], q1a[8], q2a[8];
#pragma unroll
        for (int n = 0; n < 8; ++n) { ka[n] = 0.f; q1a[n] = 0.f; q2a[n] = 0.f; }

        for (int cc0 = cs0; cc0 < cs1; cc0 += 16) {
            // wait for the oldest (current) tile: drain to 8*(inflight-1)
            switch (inflight) {
                case 4: asm volatile("s_waitcnt vmcnt(24)" ::: "memory"); break;
                case 3: asm volatile("s_waitcnt vmcnt(16)" ::: "memory"); break;
                case 2: asm volatile("s_waitcnt vmcnt(8)"  ::: "memory"); break;
                default: asm volatile("s_waitcnt vmcnt(0)" ::: "memory"); break;
            }

            // ---- read tile from LDS (swizzled), convert to bf16 A-frags ----
            const float* xb = &xbuf[w][buf][0];
            bf16x8 afr[4];
#pragma unroll
            for (int kk = 0; kk < 4; ++kk) {
                const int u0 = (kk * 8 + lk * 2)     ^ (lr & 7);
                const int u1 = (kk * 8 + lk * 2 + 1) ^ (lr & 7);
                const float4 f0 = *(const float4*)&xb[lr * 128 + u0 * 4];
                const float4 f1 = *(const float4*)&xb[lr * 128 + u1 * 4];
                bf16x8 a;
                a[0] = (__bf16)f0.x; a[1] = (__bf16)f0.y; a[2] = (__bf16)f0.z; a[3] = (__bf16)f0.w;
                a[4] = (__bf16)f1.x; a[5] = (__bf16)f1.y; a[6] = (__bf16)f1.z; a[7] = (__bf16)f1.w;
                afr[kk] = a;
            }
            asm volatile("s_waitcnt lgkmcnt(0)" ::: "memory");   // done reading buf
            inflight--;
            if (ig < NG) { issue_tile(buf); adv_issue(); inflight++; }
            buf = (buf + 1) & (RING - 1);

            // ---- MFMA: h[16 x 128] (A from DMA tile, B from regs) ----
            f32x4 acc[8];
#pragma unroll
            for (int n = 0; n < 8; ++n) { acc[n][0] = 0.f; acc[n][1] = 0.f; acc[n][2] = 0.f; acc[n][3] = 0.f; }
#pragma unroll
            for (int n = 0; n < 8; ++n)
#pragma unroll
                for (int kk = 0; kk < 4; ++kk)
                    acc[n] = __builtin_amdgcn_mfma_f32_16x16x32_bf16(afr[kk], wfr[n][kk], acc[n], 0, 0, 0);

            // ---- bias+relu, score partials (C: col=n*16+lr, row=lk*4+j) ----
            float p1[4] = {0.f, 0.f, 0.f, 0.f}, p2[4] = {0.f, 0.f, 0.f, 0.f};
#pragma unroll
            for (int n = 0; n < 8; ++n) {
#pragma unroll
                for (int j = 0; j < 4; ++j) {
                    float hv = fmaxf(acc[n][j] + br[n], 0.f);
                    acc[n][j] = hv;
                    p1[j] += hv * w1r[n];
                    p2[j] += hv * w2r[n];
                }
            }
#pragma unroll
            for (int j = 0; j < 4; ++j)
#pragma unroll
                for (int d = 1; d < 16; d <<= 1) {
                    p1[j] += __shfl_xor(p1[j], d);
                    p2[j] += __shfl_xor(p2[j], d);
                }

            // ---- per-wave online softmax over 16 rows ----
            float v1[4], v2[4];
            float r1 = -1e30f, r2 = -1e30f;
#pragma unroll
            for (int j = 0; j < 4; ++j) {
                const bool vv = (cc0 + lk * 4 + j) < cs1;
                v1[j] = vv ? p1[j] + bq1 : -1e30f;
                v2[j] = vv ? p2[j] + bq2 : -1e30f;
                r1 = fmaxf(r1, v1[j]); r2 = fmaxf(r2, v2[j]);
            }
            r1 = fmaxf(r1, __shfl_xor(r1, 16)); r1 = fmaxf(r1, __shfl_xor(r1, 32));
            r2 = fmaxf(r2, __shfl_xor(r2, 16)); r2 = fmaxf(r2, __shfl_xor(r2, 32));

            const float nm1 = fmaxf(m1, r1), nm2 = fmaxf(m2, r2);
            const float sc1 = __expf(m1 - nm1), sc2 = __expf(m2 - nm2);
            float e1j[4], e2j[4];
            float cz1 = 0.f, cz2 = 0.f;
#pragma unroll
            for (int j = 0; j < 4; ++j) {
                e1j[j] = __expf(v1[j] - nm1);
                e2j[j] = __expf(v2[j] - nm2);
                cz1 += e1j[j]; cz2 += e2j[j];
            }
            cz1 += __shfl_xor(cz1, 16); cz1 += __shfl_xor(cz1, 32);
            cz2 += __shfl_xor(cz2, 16); cz2 += __shfl_xor(cz2, 32);
            z1 = z1 * sc1 + cz1; z2 = z2 * sc2 + cz2;
            m1 = nm1; m2 = nm2;

#pragma unroll
            for (int n = 0; n < 8; ++n) {
                float kaa = 0.f, q1aa = 0.f, q2aa = 0.f;
#pragma unroll
                for (int j = 0; j < 4; ++j) {
                    const float hv = acc[n][j];
                    const bool vv = (cc0 + lk * 4 + j) < cs1;
                    kaa  += vv ? hv : 0.f;
                    q1aa += e1j[j] * hv;
                    q2aa += e2j[j] * hv;
                }
                ka[n] += kaa;
                q1a[n] = q1a[n] * sc1 + q1aa;
                q2a[n] = q2a[n] * sc2 + q2aa;
            }
        }

        // ---- writeout: reduce over lk (bits 4,5), 2 cols per lane ----
#pragma unroll
        for (int n = 0; n < 8; ++n)
#pragma unroll
            for (int d = 16; d < 64; d <<= 1) {
                ka[n]  += __shfl_xor(ka[n],  d);
                q1a[n] += __shfl_xor(q1a[n], d);
                q2a[n] += __shfl_xor(q2a[n], d);
            }
        const float inv_cnt = 1.f / fmaxf((float)cnt, 1.f);
        const float iz1 = 1.f / fmaxf(z1, 1e-12f);
        const float iz2 = 1.f / fmaxf(z2, 1e-12f);
#pragma unroll
        for (int n2 = 0; n2 < 2; ++n2) {
            const int n = lk * 2 + n2;
            const int col = n * 16 + lr;
            out[(size_t)cg * DD + col]            = ka[n]  * inv_cnt;
            out[(size_t)(NG + cg) * DD + col]     = q1a[n] * iz1;
            out[(size_t)(2 * NG + cg) * DD + col] = q2a[n] * iz2;
        }
    }
}

extern "C" void kernel_launch(void* const* d_in, const int* in_sizes, int n_in,
                              void* d_out, int out_size, void* d_ws, size_t ws_size,
                              hipStream_t stream) {
    const float* x     = (const float*)d_in[0];
    const int*   gid   = (const int*)d_in[1];
    const float* W     = (const float*)d_in[2];
    const float* b_enc = (const float*)d_in[3];
    const float* w_q1  = (const float*)d_in[4];
    const float* b_q1  = (const float*)d_in[5];
    const float* w_q2  = (const float*)d_in[6];
    const float* b_q2  = (const float*)d_in[7];
    float* out = (float*)d_out;

    int* starts        = (int*)d_ws;                                // (NG+1) ints
    unsigned short* Wl = (unsigned short*)((char*)d_ws + 131072);   // 128*128 bf16, fragment-ordered

    prep_kernel<<<65, 256, 0, stream>>>(gid, W, starts, Wl);
    fused_kernel<<<GRIDB, 128, 0, stream>>>(x, starts, Wl, b_enc, w_q1, b_q1, w_q2, b_q2, out);
}